// Round 7
// baseline (417.853 us; speedup 1.0000x reference)
//
#include <hip/hip_runtime.h>
#include <stdint.h>

#define B_ROWS 4096
#define L_FEAT 256
#define VOCAB  8192
#define ROWB   (VOCAB / 2)      // 4096 bytes per row in fp4 (2 elems/byte)
#define NSTEP  128              // K steps of 64 elems (32 B per row)

typedef __attribute__((ext_vector_type(4)))  int   intx4;
typedef __attribute__((ext_vector_type(8)))  int   intx8;
typedef __attribute__((ext_vector_type(4)))  float floatx4;
typedef __attribute__((ext_vector_type(16))) float floatx16;

// fp4 operand: HW reads only v[0:3] of the 8-reg A/B field (FMT=4) -> widen
// by duplicating the low half (no zeroing needed, upper regs ignored).
__device__ __forceinline__ intx8 widen(intx4 v) {
  return __builtin_shufflevector(v, v, 0, 1, 2, 3, 0, 1, 2, 3);
}

// ---------------- kernel 1: fused zero+scatter+sizes (fp4, 4 rows/block) -----
__global__ __launch_bounds__(256) void presence_kernel(
    const int* __restrict__ f,
    uint32_t* __restrict__ P,     // fp4 presence, ROWB bytes per row
    float* __restrict__ sizes) {
  __shared__ uint32_t rw[4][VOCAB / 8];   // 4 x 1024 words = 16 KB
  const int rbase = blockIdx.x * 4;
  const int tid = threadIdx.x;

  uint4* rp4 = (uint4*)&rw[0][0];         // 1024 uint4
  const uint4 z = make_uint4(0u, 0u, 0u, 0u);
  #pragma unroll
  for (int j = 0; j < 4; ++j) rp4[tid + j * 256] = z;
  __syncthreads();

  #pragma unroll
  for (int r = 0; r < 4; ++r) {
    const int v = f[(rbase + r) * L_FEAT + tid];     // coalesced
    atomicOr(&rw[r][v >> 3], 0x2u << ((v & 7) * 4)); // fp4 nibble 1.0; dups ok
  }
  __syncthreads();

  const int w = tid >> 6, lane = tid & 63;           // wave w owns row rbase+w
  uint4* op4 = (uint4*)(P + (size_t)(rbase + w) * (ROWB / 4));
  const uint4* sp4 = (const uint4*)&rw[w][0];        // 256 uint4
  int cnt = 0;
  #pragma unroll
  for (int q = 0; q < 4; ++q) {
    const uint4 x = sp4[lane + q * 64];
    op4[lane + q * 64] = x;
    cnt += __popc(x.x & 0x22222222u) + __popc(x.y & 0x22222222u) +
           __popc(x.z & 0x22222222u) + __popc(x.w & 0x22222222u);
  }
  #pragma unroll
  for (int off = 32; off > 0; off >>= 1) cnt += __shfl_down(cnt, off);
  if (lane == 0) sizes[rbase + w] = (float)cnt;
}

// ---------------- kernel 2: inter = P·P^T (fp4 MX MFMA) + Jaccard + mirror ---
// Round-7: BARRIER-FREE dataflow GEMM. Rounds 3/5/6 all measured ~4x the
// resource floor regardless of dtype/BK -- the cost was the per-step 4-wave
// s_barrier rendezvous at ~2 blocks/CU. Data is L2-resident (16 MB fp4), so:
//   * no LDS, no barriers: each wave computes its own 64x64 quadrant of the
//     128x128 supertile with operands loaded DIRECTLY global->VGPR.
//   * fully-unrolled K loop: all 512 load offsets are compile-time immediates
//     (max 4064 < 4095) off 4 per-lane base pointers -> zero address VALU.
//   * software pipeline depth 3 via 4-slot rotating register arrays (static
//     indices only); compiler's dependency-driven vmcnt does the scheduling.
//   * L2 sharing replaces LDS sharing: quadrant waves re-read the same panel
//     rows through L1/L2 (~540 MB total ~= 39% of L2 ceiling at target pace).
//   * XCD swizzle, setprio on MFMA, nt stores, fused mirror (all verified).
__global__ __launch_bounds__(256, 3) void gemm_kernel(
    const unsigned char* __restrict__ P,
    const float* __restrict__ sizes,
    float* __restrict__ out) {
  // XCD swizzle (528 = 8*66 -> bijective) then triangle decode, bx >= by
  int bid = blockIdx.x;
  bid = (bid & 7) * 66 + (bid >> 3);
  int b = bid, by = 0, rem = 32;
  while (b >= rem) { b -= rem; ++by; --rem; }
  const int bx = by + b;

  const int tid  = threadIdx.x;
  const int wave = tid >> 6, lane = tid & 63;
  const int wm = wave >> 1, wn = wave & 1;   // quadrant of the 128x128 tile
  const int r31 = lane & 31, khalf = lane >> 5;

  const int iB = by * 128 + wm * 64;   // this wave's output rows
  const int jB = bx * 128 + wn * 64;   // this wave's output cols

  // per-lane base pointers: row-major fp4 P, lane covers (row, khalf*16 + k)
  const unsigned char* pA0 = P + (size_t)(iB + r31) * ROWB + khalf * 16;
  const unsigned char* pA1 = pA0 + (size_t)32 * ROWB;
  const unsigned char* pB0 = P + (size_t)(jB + r31) * ROWB + khalf * 16;
  const unsigned char* pB1 = pB0 + (size_t)32 * ROWB;

  floatx16 acc[2][2];
  #pragma unroll
  for (int ai = 0; ai < 2; ++ai)
    #pragma unroll
    for (int ci = 0; ci < 2; ++ci)
      #pragma unroll
      for (int e = 0; e < 16; ++e) acc[ai][ci][e] = 0.f;

  // rotating 4-slot register pipeline, prefetch depth 3
  intx4 a0[4], a1[4], b0[4], b1[4];

  #pragma unroll
  for (int k = 0; k < 3; ++k) {      // prologue: slots 0..2 <- steps 0..2
    a0[k] = *(const intx4*)(pA0 + k * 32);
    a1[k] = *(const intx4*)(pA1 + k * 32);
    b0[k] = *(const intx4*)(pB0 + k * 32);
    b1[k] = *(const intx4*)(pB1 + k * 32);
  }

  #pragma unroll
  for (int k = 0; k < NSTEP; ++k) {
    if (k + 3 < NSTEP) {             // prefetch step k+3 (compile-time offset)
      const int s = (k + 3) & 3;
      const int off = (k + 3) * 32;
      a0[s] = *(const intx4*)(pA0 + off);
      a1[s] = *(const intx4*)(pA1 + off);
      b0[s] = *(const intx4*)(pB0 + off);
      b1[s] = *(const intx4*)(pB1 + off);
    }
    const int s = k & 3;
    const intx8 A0 = widen(a0[s]), A1 = widen(a1[s]);
    const intx8 B0 = widen(b0[s]), B1 = widen(b1[s]);
    __builtin_amdgcn_s_setprio(1);
    acc[0][0] = __builtin_amdgcn_mfma_scale_f32_32x32x64_f8f6f4(
        A0, B0, acc[0][0], 4, 4, 0, 127, 0, 127);
    acc[0][1] = __builtin_amdgcn_mfma_scale_f32_32x32x64_f8f6f4(
        A0, B1, acc[0][1], 4, 4, 0, 127, 0, 127);
    acc[1][0] = __builtin_amdgcn_mfma_scale_f32_32x32x64_f8f6f4(
        A1, B0, acc[1][0], 4, 4, 0, 127, 0, 127);
    acc[1][1] = __builtin_amdgcn_mfma_scale_f32_32x32x64_f8f6f4(
        A1, B1, acc[1][1], 4, 4, 0, 127, 0, 127);
    __builtin_amdgcn_s_setprio(0);
  }

  // epilogue (verified rounds 5/6): sim = -inter/(|A_i|+|A_j|-inter) + mirror.
  // 32x32 C layout: col = lane&31, row = (reg&3) + 8*(reg>>2) + 4*(lane>>5).
  #pragma unroll
  for (int tm = 0; tm < 2; ++tm) {
    const int rowb = iB + tm * 32 + 4 * khalf;
    #pragma unroll
    for (int tn = 0; tn < 2; ++tn) {
      const int colb = jB + tn * 32 + r31;
      const float sj = sizes[colb];
      #pragma unroll
      for (int q = 0; q < 4; ++q) {           // reg quads: rows rq..rq+3
        const int rq = rowb + 8 * q;
        floatx4 tv;
        #pragma unroll
        for (int j = 0; j < 4; ++j) {
          const float inter = acc[tm][tn][4 * q + j];
          const float u = sizes[rq + j] + sj - inter;
          tv[j] = (u != 0.f) ? (-inter / u) : 0.f;
        }
        __builtin_nontemporal_store(tv[0], &out[(size_t)(rq + 0) * B_ROWS + colb]);
        __builtin_nontemporal_store(tv[1], &out[(size_t)(rq + 1) * B_ROWS + colb]);
        __builtin_nontemporal_store(tv[2], &out[(size_t)(rq + 2) * B_ROWS + colb]);
        __builtin_nontemporal_store(tv[3], &out[(size_t)(rq + 3) * B_ROWS + colb]);
        // mirrored: 4 row-values contiguous in the transposed row (16B-aligned)
        __builtin_nontemporal_store(tv, (floatx4*)&out[(size_t)colb * B_ROWS + rq]);
      }
    }
  }
}

// ---------------- launcher ---------------------------------------------------
extern "C" void kernel_launch(void* const* d_in, const int* in_sizes, int n_in,
                              void* d_out, int out_size, void* d_ws, size_t ws_size,
                              hipStream_t stream) {
  const int* features = (const int*)d_in[0];
  float* out = (float*)d_out;
  uint32_t* P = (uint32_t*)d_ws;                                  // 16 MB fp4
  float* sizes = (float*)((char*)d_ws + (size_t)B_ROWS * ROWB);   // +16 KB

  presence_kernel<<<B_ROWS / 4, 256, 0, stream>>>(features, P, sizes);
  gemm_kernel<<<528, 256, 0, stream>>>((const unsigned char*)P, sizes, out);
}

// Round 8
// 224.680 us; speedup vs baseline: 1.8598x; 1.8598x over previous
//
#include <hip/hip_runtime.h>
#include <stdint.h>

#define B_ROWS 4096
#define L_FEAT 256
#define VOCAB  8192
#define ROWB   (VOCAB / 2)      // 4096 bytes per row in fp4 (2 elems/byte)
#define BM 128
#define BN 128
#define BKE 128                 // K elements per step (2 MFMA-K)
#define BKB 64                  // K bytes per step per row
#define NSTEP (VOCAB / BKE)     // 64

typedef __attribute__((ext_vector_type(4)))  int   intx4;
typedef __attribute__((ext_vector_type(8)))  int   intx8;
typedef __attribute__((ext_vector_type(4)))  float floatx4;
typedef __attribute__((ext_vector_type(16))) float floatx16;

// fp4 operand: HW reads only v[0:3] of the 8-reg A/B field (FMT=4) -> widen
// by duplicating the low half (verified round 7: passed, absmax 0).
__device__ __forceinline__ intx8 widen(intx4 v) {
  return __builtin_shufflevector(v, v, 0, 1, 2, 3, 0, 1, 2, 3);
}

__device__ __forceinline__ void async_copy16(const void* gsrc, void* ldst) {
  __builtin_amdgcn_global_load_lds(
      (const __attribute__((address_space(1))) void*)gsrc,
      (__attribute__((address_space(3))) void*)ldst, 16, 0, 0);
}

// ---------------- kernel 1: fused zero+scatter+sizes (fp4, 4 rows/block) -----
// (verified rounds 6/7)
__global__ __launch_bounds__(256) void presence_kernel(
    const int* __restrict__ f,
    uint32_t* __restrict__ P,     // fp4 presence, ROWB bytes per row
    float* __restrict__ sizes) {
  __shared__ uint32_t rw[4][VOCAB / 8];   // 4 x 1024 words = 16 KB
  const int rbase = blockIdx.x * 4;
  const int tid = threadIdx.x;

  uint4* rp4 = (uint4*)&rw[0][0];         // 1024 uint4
  const uint4 z = make_uint4(0u, 0u, 0u, 0u);
  #pragma unroll
  for (int j = 0; j < 4; ++j) rp4[tid + j * 256] = z;
  __syncthreads();

  #pragma unroll
  for (int r = 0; r < 4; ++r) {
    const int v = f[(rbase + r) * L_FEAT + tid];     // coalesced
    atomicOr(&rw[r][v >> 3], 0x2u << ((v & 7) * 4)); // fp4 nibble 1.0; dups ok
  }
  __syncthreads();

  const int w = tid >> 6, lane = tid & 63;           // wave w owns row rbase+w
  uint4* op4 = (uint4*)(P + (size_t)(rbase + w) * (ROWB / 4));
  const uint4* sp4 = (const uint4*)&rw[w][0];        // 256 uint4
  int cnt = 0;
  #pragma unroll
  for (int q = 0; q < 4; ++q) {
    const uint4 x = sp4[lane + q * 64];
    op4[lane + q * 64] = x;
    cnt += __popc(x.x & 0x22222222u) + __popc(x.y & 0x22222222u) +
           __popc(x.z & 0x22222222u) + __popc(x.w & 0x22222222u);
  }
  #pragma unroll
  for (int off = 32; off > 0; off >>= 1) cnt += __shfl_down(cnt, off);
  if (lane == 0) sizes[rbase + w] = (float)cnt;
}

// ---------------- kernel 2: inter = P·P^T (fp4 MX MFMA) + Jaccard + mirror ---
// Round-8: fp4 payload in the round-0/3 PROVEN schedule shape — fat steps,
// dumb-simple sync. Per step (BK=128 elems): 8 ds_read_b128 + 4 stage ops +
// 8 MFMA per wave, ONE __syncthreads at step end (compiler-managed waits; the
// end-of-step drain is harmless because the step (~1160 cyc of LDS service)
// far exceeds L2 latency — this is what rounds 0/3 proved and rounds 1/5/6's
// hand-rolled vmcnt pipelines kept breaking).
//   * 2 buffers x 16 KB = 32 KB LDS -> cap 5 blocks/CU, no occupancy tail.
//   * hazards: reads(cur) vs stage writes(cur^1); barrier at end of each step
//     separates both WAR and RAW pairs (one barrier per step suffices).
//   * fragment-linear LDS chunks (1 KB, lane*16) — conflict-free (r6-verified).
//   * XCD swizzle, setprio on MFMA, nt stores, fused mirror (all verified).
__global__ __launch_bounds__(256) void gemm_kernel(
    const unsigned char* __restrict__ P,
    const float* __restrict__ sizes,
    float* __restrict__ out) {
  // XCD swizzle (528 = 8*66 -> bijective) then triangle decode, bx >= by
  int bid = blockIdx.x;
  bid = (bid & 7) * 66 + (bid >> 3);
  int b = bid, by = 0, rem = 32;
  while (b >= rem) { b -= rem; ++by; --rem; }
  const int bx = by + b;
  const int iBase = by * BM;   // output rows
  const int jBase = bx * BN;   // output cols

  // chunk(c) = (frag f = c>>1, kk = c&1): 1 KB, lane-linear
  __shared__ __align__(16) unsigned char As[2][8192];  // 8 chunks x 1 KB
  __shared__ __align__(16) unsigned char Bs[2][8192];

  const int tid  = threadIdx.x;
  const int wave = tid >> 6, lane = tid & 63;
  const int wm = wave >> 1, wn = wave & 1;   // 2x2 wave grid, each wave 64x64
  const int r31 = lane & 31, khalf = lane >> 5;

  floatx16 acc[2][2];
  #pragma unroll
  for (int ai = 0; ai < 2; ++ai)
    #pragma unroll
    for (int ci = 0; ci < 2; ++ci)
      #pragma unroll
      for (int e = 0; e < 16; ++e) acc[ai][ci][e] = 0.f;

  // staging: wave w copies chunks {w, w+4} of A and of B (4 ops/wave/step).
  // chunk c source for lane l: row (c>>1)*32 + (l&31), bytes
  // k0b + (c&1)*32 + (l>>5)*16; LDS dst = chunk_base + lane*16 (r6-verified).
  const int c0 = wave, c1 = wave + 4;
  const unsigned char* srcA0 =
      P + (size_t)(iBase + (c0 >> 1) * 32 + r31) * ROWB + (c0 & 1) * 32 + khalf * 16;
  const unsigned char* srcA1 =
      P + (size_t)(iBase + (c1 >> 1) * 32 + r31) * ROWB + (c1 & 1) * 32 + khalf * 16;
  const unsigned char* srcB0 =
      P + (size_t)(jBase + (c0 >> 1) * 32 + r31) * ROWB + (c0 & 1) * 32 + khalf * 16;
  const unsigned char* srcB1 =
      P + (size_t)(jBase + (c1 >> 1) * 32 + r31) * ROWB + (c1 & 1) * 32 + khalf * 16;

  #define STAGE(buf, k0b)                                                     \
    {                                                                         \
      async_copy16(srcA0 + (k0b), &As[buf][c0 * 1024]);                       \
      async_copy16(srcA1 + (k0b), &As[buf][c1 * 1024]);                       \
      async_copy16(srcB0 + (k0b), &Bs[buf][c0 * 1024]);                       \
      async_copy16(srcB1 + (k0b), &Bs[buf][c1 * 1024]);                       \
    }

  STAGE(0, 0);          // prologue: stage step 0
  __syncthreads();      // (drains vmcnt0 — once, outside the loop)

  int cur = 0;
  for (int i = 0; i < NSTEP; ++i) {
    // fragment reads for step i: lane-linear ds_read_b128, conflict-free
    intx4 a4[2][2], b4[2][2];   // [tm|tn][kk]
    #pragma unroll
    for (int t = 0; t < 2; ++t)
      #pragma unroll
      for (int kk = 0; kk < 2; ++kk) {
        a4[t][kk] = *(const intx4*)
            &As[cur][((wm * 2 + t) * 2 + kk) * 1024 + lane * 16];
        b4[t][kk] = *(const intx4*)
            &Bs[cur][((wn * 2 + t) * 2 + kk) * 1024 + lane * 16];
      }

    // stage step i+1 into the other buffer (wraps harmlessly at the end);
    // in flight for the whole step, drained by the barrier below.
    STAGE(cur ^ 1, ((i + 1) * BKB) & (ROWB - 1));

    __builtin_amdgcn_s_setprio(1);
    #pragma unroll
    for (int kk = 0; kk < 2; ++kk) {
      const intx8 A0 = widen(a4[0][kk]), A1 = widen(a4[1][kk]);
      const intx8 B0 = widen(b4[0][kk]), B1 = widen(b4[1][kk]);
      acc[0][0] = __builtin_amdgcn_mfma_scale_f32_32x32x64_f8f6f4(
          A0, B0, acc[0][0], 4, 4, 0, 127, 0, 127);
      acc[0][1] = __builtin_amdgcn_mfma_scale_f32_32x32x64_f8f6f4(
          A0, B1, acc[0][1], 4, 4, 0, 127, 0, 127);
      acc[1][0] = __builtin_amdgcn_mfma_scale_f32_32x32x64_f8f6f4(
          A1, B0, acc[1][0], 4, 4, 0, 127, 0, 127);
      acc[1][1] = __builtin_amdgcn_mfma_scale_f32_32x32x64_f8f6f4(
          A1, B1, acc[1][1], 4, 4, 0, 127, 0, 127);
    }
    __builtin_amdgcn_s_setprio(0);

    __syncthreads();    // one barrier per step: WAR+RAW for both buffers
    cur ^= 1;
  }

  // epilogue (verified rounds 5/6): sim = -inter/(|A_i|+|A_j|-inter) + mirror.
  // 32x32 C layout: col = lane&31, row = (reg&3) + 8*(reg>>2) + 4*(lane>>5).
  #pragma unroll
  for (int tm = 0; tm < 2; ++tm) {
    const int rowb = iBase + wm * 64 + tm * 32 + 4 * khalf;
    #pragma unroll
    for (int tn = 0; tn < 2; ++tn) {
      const int colb = jBase + wn * 64 + tn * 32 + r31;
      const float sj = sizes[colb];
      #pragma unroll
      for (int q = 0; q < 4; ++q) {           // reg quads: rows rq..rq+3
        const int rq = rowb + 8 * q;
        floatx4 tv;
        #pragma unroll
        for (int j = 0; j < 4; ++j) {
          const float inter = acc[tm][tn][4 * q + j];
          const float u = sizes[rq + j] + sj - inter;
          tv[j] = (u != 0.f) ? (-inter / u) : 0.f;
        }
        __builtin_nontemporal_store(tv[0], &out[(size_t)(rq + 0) * B_ROWS + colb]);
        __builtin_nontemporal_store(tv[1], &out[(size_t)(rq + 1) * B_ROWS + colb]);
        __builtin_nontemporal_store(tv[2], &out[(size_t)(rq + 2) * B_ROWS + colb]);
        __builtin_nontemporal_store(tv[3], &out[(size_t)(rq + 3) * B_ROWS + colb]);
        // mirrored: 4 row-values contiguous in the transposed row (16B-aligned)
        __builtin_nontemporal_store(tv, (floatx4*)&out[(size_t)colb * B_ROWS + rq]);
      }
    }
  }
}

// ---------------- launcher ---------------------------------------------------
extern "C" void kernel_launch(void* const* d_in, const int* in_sizes, int n_in,
                              void* d_out, int out_size, void* d_ws, size_t ws_size,
                              hipStream_t stream) {
  const int* features = (const int*)d_in[0];
  float* out = (float*)d_out;
  uint32_t* P = (uint32_t*)d_ws;                                  // 16 MB fp4
  float* sizes = (float*)((char*)d_ws + (size_t)B_ROWS * ROWB);   // +16 KB

  presence_kernel<<<B_ROWS / 4, 256, 0, stream>>>(features, P, sizes);
  gemm_kernel<<<528, 256, 0, stream>>>((const unsigned char*)P, sizes, out);
}